// Round 3
// baseline (665.737 us; speedup 1.0000x reference)
//
#include <hip/hip_runtime.h>

// ---------------------------------------------------------------------------
// GAT_4733053960619: SAGEConv(mean) -> ELU -> GAT(2 heads,64) -> ELU -> GAT(1,47)
// N=50000, E=800000, IN_FEATS=256. All fp32.
//
// R2: GEMM rebuilt. TM=8xTN=8 register tile (flop/LDS-byte = 2.0, VALU-bound),
// split fragments at tc*4 / BN/2+tc*4 (2-way bank aliasing = free), float4
// global loads with register-staged prefetch, L0's two GEMMs fused into one
// launch via blockIdx.y. attn kernels cache logits to halve gathers.
// ---------------------------------------------------------------------------

__device__ __forceinline__ float wave_sum(float v) {
#pragma unroll
  for (int o = 32; o > 0; o >>= 1) v += __shfl_xor(v, o, 64);
  return v;
}

__device__ __forceinline__ float elu_f(float v) {
  return v > 0.f ? v : __expf(v) - 1.0f;
}

// ---------------- CSR build ----------------
__global__ __launch_bounds__(256) void deg_kernel(const int* __restrict__ dst,
                                                  int* __restrict__ deg, int E) {
  int i = blockIdx.x * 256 + threadIdx.x;
  if (i < E) atomicAdd(&deg[dst[i]], 1);
}

// single-block scan, wave-shuffle based
__global__ __launch_bounds__(1024) void scan_kernel(const int* __restrict__ deg,
                                                    int* __restrict__ row_start, int n) {
  __shared__ int wsum[16];
  __shared__ int wpre[16];
  __shared__ int s_carry;
  const int t = threadIdx.x;
  const int lane = t & 63;
  const int w = t >> 6;
  if (t == 0) s_carry = 0;
  __syncthreads();
  for (int base = 0; base < n; base += 1024) {
    int v = (base + t < n) ? deg[base + t] : 0;
    int inc = v;
#pragma unroll
    for (int o = 1; o < 64; o <<= 1) {
      int u = __shfl_up(inc, o, 64);
      if (lane >= o) inc += u;
    }
    if (lane == 63) wsum[w] = inc;
    __syncthreads();
    if (w == 0 && lane < 16) {
      int s = wsum[lane];
      int p = s;
#pragma unroll
      for (int o = 1; o < 16; o <<= 1) {
        int u = __shfl_up(p, o, 64);
        if (lane >= o) p += u;
      }
      wpre[lane] = p - s;
    }
    __syncthreads();
    int carry = s_carry;
    if (base + t < n) row_start[base + t] = carry + wpre[w] + inc - v;
    __syncthreads();
    if (t == 1023) s_carry = carry + wpre[15] + inc;
    __syncthreads();
  }
  if (t == 0) row_start[n] = s_carry;
}

__global__ __launch_bounds__(256) void scatter_kernel(const int* __restrict__ src,
                                                      const int* __restrict__ dst,
                                                      const int* __restrict__ row_start,
                                                      int* __restrict__ cursor,
                                                      int* __restrict__ csr_src, int E) {
  int i = blockIdx.x * 256 + threadIdx.x;
  if (i < E) {
    int d = dst[i];
    int p = atomicAdd(&cursor[d], 1);
    csr_src[row_start[d] + p] = src[i];
  }
}

// ---------------- fp32 register-tiled GEMM, TM x TN = 8x8 or 8x4 -----------
// C = A @ W. blockIdx.y picks {W0,C0,ilv0} or {W1,C1,ilv1}.
// ilv: logical col gc stored at (gc&63)*2+(gc>>6)  (requires N==128, TN==8).
// Fragment split: cols tc*4 and BN/2+tc*4; rows tr*4 and BM/2+tr*4.
template <int BM, int BN, int BK, int TM, int TN>
__global__ __launch_bounds__((BM / TM) * (BN / TN)) void gemm_f32(
    const float* __restrict__ A, int lda,
    const float* __restrict__ W0, const float* __restrict__ W1, int ldw,
    float* __restrict__ C0, float* __restrict__ C1, int ldc,
    int M, int N, int K, int ilv0, int ilv1) {
  constexpr int THREADS = (BM / TM) * (BN / TN);
  constexpr int TCN = BN / TN;
  constexpr int A4 = BM * BK / 4 / THREADS;
  constexpr int W4 = BK * BN / 4 / THREADS;
  static_assert(TM == 8 && (TN == 8 || TN == 4), "layout");
  __shared__ float As[BK][BM + 4];
  __shared__ float Ws[BK][BN + 4];

  const float* W = blockIdx.y ? W1 : W0;
  float* C = blockIdx.y ? C1 : C0;
  const int ilv = blockIdx.y ? ilv1 : ilv0;

  const int tid = threadIdx.x;
  const int tc = tid % TCN;
  const int tr = tid / TCN;
  const int row0 = blockIdx.x * BM;

  float4 pa[A4], pw[W4];

  auto loadA = [&](int k0) {
#pragma unroll
    for (int q = 0; q < A4; ++q) {
      int j = tid + q * THREADS;
      int r = j >> 2, kq = j & 3;  // BK==16: 4 float4 per row
      int gr = row0 + r;
      if (gr < M)
        pa[q] = *(const float4*)&A[(size_t)gr * lda + k0 + kq * 4];
      else
        pa[q] = make_float4(0.f, 0.f, 0.f, 0.f);
    }
  };
  auto storeA = [&]() {
#pragma unroll
    for (int q = 0; q < A4; ++q) {
      int j = tid + q * THREADS;
      int r = j >> 2, kq = j & 3;
      As[kq * 4 + 0][r] = pa[q].x;
      As[kq * 4 + 1][r] = pa[q].y;
      As[kq * 4 + 2][r] = pa[q].z;
      As[kq * 4 + 3][r] = pa[q].w;
    }
  };
  auto loadW = [&](int k0) {
#pragma unroll
    for (int q = 0; q < W4; ++q) {
      int j = tid + q * THREADS;
      int r = j / (BN / 4), c4 = j % (BN / 4);
      int gc = c4 * 4;
      const float* wr = W + (size_t)(k0 + r) * ldw + gc;
      if (((ldw & 3) == 0) && gc + 3 < N) {
        pw[q] = *(const float4*)wr;
      } else {
        float4 v = make_float4(0.f, 0.f, 0.f, 0.f);
        if (gc < N) v.x = wr[0];
        if (gc + 1 < N) v.y = wr[1];
        if (gc + 2 < N) v.z = wr[2];
        if (gc + 3 < N) v.w = wr[3];
        pw[q] = v;
      }
    }
  };
  auto storeW = [&]() {
#pragma unroll
    for (int q = 0; q < W4; ++q) {
      int j = tid + q * THREADS;
      int r = j / (BN / 4), c4 = j % (BN / 4);
      *(float4*)&Ws[r][c4 * 4] = pw[q];
    }
  };

  float acc[TM][TN] = {};
  const int nt = K / BK;

  loadA(0);
  loadW(0);
  storeA();
  storeW();
  __syncthreads();

  for (int t = 0; t < nt; ++t) {
    if (t + 1 < nt) {
      loadA((t + 1) * BK);
      loadW((t + 1) * BK);
    }
#pragma unroll
    for (int kk = 0; kk < BK; ++kk) {
      float4 aL = *(const float4*)&As[kk][tr * 4];
      float4 aH = *(const float4*)&As[kk][BM / 2 + tr * 4];
      float4 bL = *(const float4*)&Ws[kk][tc * 4];
      float a[TM], b[TN];
      a[0] = aL.x; a[1] = aL.y; a[2] = aL.z; a[3] = aL.w;
      a[4] = aH.x; a[5] = aH.y; a[6] = aH.z; a[7] = aH.w;
      b[0] = bL.x; b[1] = bL.y; b[2] = bL.z; b[3] = bL.w;
      if constexpr (TN == 8) {
        float4 bH = *(const float4*)&Ws[kk][BN / 2 + tc * 4];
        b[4] = bH.x; b[5] = bH.y; b[6] = bH.z; b[7] = bH.w;
      }
#pragma unroll
      for (int i = 0; i < TM; i++)
#pragma unroll
        for (int j = 0; j < TN; j++) acc[i][j] = fmaf(a[i], b[j], acc[i][j]);
    }
    __syncthreads();
    if (t + 1 < nt) {
      storeA();
      storeW();
      __syncthreads();
    }
  }

#pragma unroll
  for (int i = 0; i < TM; ++i) {
    int gr = row0 + (i < 4 ? tr * 4 + i : BM / 2 + tr * 4 + (i - 4));
    if (gr >= M) continue;
    float* crow = C + (size_t)gr * ldc;
    if (TN == 8 && ilv) {
#pragma unroll
      for (int j = 0; j < 4; ++j) {
        int gcl = tc * 4 + j;
        *(float2*)&crow[gcl * 2] = make_float2(acc[i][j], acc[i][j + 4]);
      }
    } else {
      int gc0 = tc * 4;
      if (gc0 + 3 < N) {
        *(float4*)&crow[gc0] = make_float4(acc[i][0], acc[i][1], acc[i][2], acc[i][3]);
      } else {
#pragma unroll
        for (int j = 0; j < 4; ++j)
          if (gc0 + j < N) crow[gc0 + j] = acc[i][j];
      }
      if constexpr (TN == 8) {
        int gc1 = BN / 2 + tc * 4;
        if (gc1 + 3 < N) {
          *(float4*)&crow[gc1] = make_float4(acc[i][4], acc[i][5], acc[i][6], acc[i][7]);
        } else {
#pragma unroll
          for (int j = 0; j < 4; ++j)
            if (gc1 + j < N) crow[gc1 + j] = acc[i][4 + j];
        }
      }
    }
  }
}

// ---------------- SAGE aggregation (wave per node) ----------------
__global__ __launch_bounds__(256) void sage_agg(const float* __restrict__ z,
                                                const float2* __restrict__ yI,
                                                const int* __restrict__ row_start,
                                                const int* __restrict__ csr_src,
                                                const float* __restrict__ b,
                                                float* __restrict__ h0, int N) {
  int wid = threadIdx.x >> 6;
  int lane = threadIdx.x & 63;
  int n = blockIdx.x * 4 + wid;
  if (n >= N) return;
  int s = row_start[n], e = row_start[n + 1];
  float a0 = 0.f, a1 = 0.f;
  int i = s;
  for (; i + 1 < e; i += 2) {
    int u0 = csr_src[i], u1 = csr_src[i + 1];
    float2 f0 = yI[(size_t)u0 * 64 + lane];
    float2 f1 = yI[(size_t)u1 * 64 + lane];
    a0 += f0.x + f1.x;
    a1 += f0.y + f1.y;
  }
  if (i < e) {
    float2 f = yI[(size_t)csr_src[i] * 64 + lane];
    a0 += f.x;
    a1 += f.y;
  }
  float inv = 1.0f / fmaxf((float)(e - s), 1.0f);
  size_t base = (size_t)n * 128;
  float v0 = z[base + lane] + a0 * inv + b[lane];
  float v1 = z[base + 64 + lane] + a1 * inv + b[64 + lane];
  h0[base + lane] = elu_f(v0);
  h0[base + 64 + lane] = elu_f(v1);
}

// ---------------- per-node attention logits (layer 1) ----------------------
__global__ __launch_bounds__(256) void elr1_kernel(const float2* __restrict__ featI,
                                                   const float* __restrict__ al,
                                                   const float* __restrict__ ar,
                                                   float2* __restrict__ el,
                                                   float2* __restrict__ er, int N) {
  int wid = threadIdx.x >> 6;
  int lane = threadIdx.x & 63;
  int n = blockIdx.x * 4 + wid;
  if (n >= N) return;
  float2 f = featI[(size_t)n * 64 + lane];
  float e0 = wave_sum(f.x * al[lane]);
  float e1 = wave_sum(f.y * al[64 + lane]);
  float r0 = wave_sum(f.x * ar[lane]);
  float r1 = wave_sum(f.y * ar[64 + lane]);
  if (lane == 0) {
    el[n] = make_float2(e0, e1);
    er[n] = make_float2(r0, r1);
  }
}

// ---------------- attn1: thread per node, softmax weights ------------------
__global__ __launch_bounds__(256) void attn1_kernel(const float2* __restrict__ el,
                                                    const float2* __restrict__ er,
                                                    const int* __restrict__ row_start,
                                                    const int* __restrict__ csr_src,
                                                    float2* __restrict__ alpha,
                                                    float2* __restrict__ inv_s, int N) {
  int n = blockIdx.x * 256 + threadIdx.x;
  if (n >= N) return;
  int beg = row_start[n], end = row_start[n + 1];
  float2 r = er[n];
  float m0 = -INFINITY, m1 = -INFINITY;
  for (int i = beg; i < end; ++i) {
    float2 l = el[csr_src[i]];
    float e0 = l.x + r.x;
    e0 = e0 > 0.f ? e0 : 0.2f * e0;
    float e1 = l.y + r.y;
    e1 = e1 > 0.f ? e1 : 0.2f * e1;
    alpha[i] = make_float2(e0, e1);  // cache logits (sequential)
    m0 = fmaxf(m0, e0);
    m1 = fmaxf(m1, e1);
  }
  float s0 = 0.f, s1 = 0.f;
  for (int i = beg; i < end; ++i) {
    float2 a = alpha[i];
    float p0 = __expf(a.x - m0);
    float p1 = __expf(a.y - m1);
    s0 += p0;
    s1 += p1;
    alpha[i] = make_float2(p0, p1);
  }
  inv_s[n] = make_float2(1.0f / fmaxf(s0, 1e-9f), 1.0f / fmaxf(s1, 1e-9f));
}

// ---------------- fused GAT layer 1 aggregation (wave per node) ------------
__global__ __launch_bounds__(256) void gat1_agg(const float2* __restrict__ featI,
                                                const float2* __restrict__ alpha,
                                                const float2* __restrict__ inv_s,
                                                const int* __restrict__ row_start,
                                                const int* __restrict__ csr_src,
                                                const float* __restrict__ b,
                                                float* __restrict__ h1, int N) {
  int wid = threadIdx.x >> 6;
  int lane = threadIdx.x & 63;
  int n = blockIdx.x * 4 + wid;
  if (n >= N) return;
  int beg = row_start[n], end = row_start[n + 1];
  float a0 = 0.f, a1 = 0.f;
  int i = beg;
  for (; i + 1 < end; i += 2) {
    int u0 = csr_src[i], u1 = csr_src[i + 1];
    float2 p0 = alpha[i], p1 = alpha[i + 1];
    float2 f0 = featI[(size_t)u0 * 64 + lane];
    float2 f1 = featI[(size_t)u1 * 64 + lane];
    a0 = fmaf(p0.x, f0.x, a0);
    a1 = fmaf(p0.y, f0.y, a1);
    a0 = fmaf(p1.x, f1.x, a0);
    a1 = fmaf(p1.y, f1.y, a1);
  }
  if (i < end) {
    float2 p = alpha[i];
    float2 f = featI[(size_t)csr_src[i] * 64 + lane];
    a0 = fmaf(p.x, f.x, a0);
    a1 = fmaf(p.y, f.y, a1);
  }
  float2 is = inv_s[n];
  float o0 = a0 * is.x + b[lane];
  float o1 = a1 * is.y + b[64 + lane];
  size_t base = (size_t)n * 128;
  h1[base + lane] = elu_f(o0);
  h1[base + 64 + lane] = elu_f(o1);
}

// ---------------- per-node attention logits (layer 2) ----------------------
__global__ __launch_bounds__(256) void elr2_kernel(const float* __restrict__ feat,  // ld 48
                                                   const float* __restrict__ al,
                                                   const float* __restrict__ ar,
                                                   float* __restrict__ el,
                                                   float* __restrict__ er, int N) {
  int wid = threadIdx.x >> 6;
  int lane = threadIdx.x & 63;
  int n = blockIdx.x * 4 + wid;
  if (n >= N) return;
  float f = 0.f, a = 0.f, r = 0.f;
  if (lane < 47) {
    f = feat[(size_t)n * 48 + lane];
    a = al[lane];
    r = ar[lane];
  }
  float e = wave_sum(f * a);
  float rr = wave_sum(f * r);
  if (lane == 0) {
    el[n] = e;
    er[n] = rr;
  }
}

// ---------------- attn2: thread per node ----------------------------------
__global__ __launch_bounds__(256) void attn2_kernel(const float* __restrict__ el,
                                                    const float* __restrict__ er,
                                                    const int* __restrict__ row_start,
                                                    const int* __restrict__ csr_src,
                                                    float* __restrict__ alpha,
                                                    float* __restrict__ inv_s, int N) {
  int n = blockIdx.x * 256 + threadIdx.x;
  if (n >= N) return;
  int beg = row_start[n], end = row_start[n + 1];
  float r = er[n];
  float m = -INFINITY;
  for (int i = beg; i < end; ++i) {
    float e = el[csr_src[i]] + r;
    e = e > 0.f ? e : 0.2f * e;
    alpha[i] = e;
    m = fmaxf(m, e);
  }
  float s = 0.f;
  for (int i = beg; i < end; ++i) {
    float p = __expf(alpha[i] - m);
    s += p;
    alpha[i] = p;
  }
  inv_s[n] = 1.0f / fmaxf(s, 1e-9f);
}

// ---------------- fused GAT layer 2 aggregation -> d_out ------------------
__global__ __launch_bounds__(256) void gat2_agg(const float* __restrict__ feat,  // ld 48
                                                const float* __restrict__ alpha,
                                                const float* __restrict__ inv_s,
                                                const int* __restrict__ row_start,
                                                const int* __restrict__ csr_src,
                                                const float* __restrict__ b,
                                                float* __restrict__ out, int N) {
  int wid = threadIdx.x >> 6;
  int lane = threadIdx.x & 63;
  int n = blockIdx.x * 4 + wid;
  if (n >= N) return;
  int beg = row_start[n], end = row_start[n + 1];
  int lidx = lane < 47 ? lane : 0;
  float acc = 0.f;
  int i = beg;
  for (; i + 1 < end; i += 2) {
    int u0 = csr_src[i], u1 = csr_src[i + 1];
    float p0 = alpha[i], p1 = alpha[i + 1];
    acc = fmaf(p0, feat[(size_t)u0 * 48 + lidx], acc);
    acc = fmaf(p1, feat[(size_t)u1 * 48 + lidx], acc);
  }
  if (i < end) {
    acc = fmaf(alpha[i], feat[(size_t)csr_src[i] * 48 + lidx], acc);
  }
  if (lane < 47) {
    out[(size_t)n * 47 + lane] = acc * inv_s[n] + b[lane];
  }
}

// ---------------------------------------------------------------------------
extern "C" void kernel_launch(void* const* d_in, const int* in_sizes, int n_in,
                              void* d_out, int out_size, void* d_ws, size_t ws_size,
                              hipStream_t stream) {
  const float* x = (const float*)d_in[0];
  const int* src = (const int*)d_in[1];
  const int* dst = (const int*)d_in[2];
  const float* sage_w_self = (const float*)d_in[3];
  const float* sage_w_neigh = (const float*)d_in[4];
  const float* sage_b = (const float*)d_in[5];
  const float* gat1_w = (const float*)d_in[6];
  const float* gat1_al = (const float*)d_in[7];
  const float* gat1_ar = (const float*)d_in[8];
  const float* gat1_b = (const float*)d_in[9];
  const float* gat2_w = (const float*)d_in[10];
  const float* gat2_al = (const float*)d_in[11];
  const float* gat2_ar = (const float*)d_in[12];
  const float* gat2_b = (const float*)d_in[13];
  float* out = (float*)d_out;

  const int N = in_sizes[0] / 256;
  const int E = in_sizes[1];

  char* ws = (char*)d_ws;
  size_t off = 0;
  auto alloc = [&](size_t bytes) {
    size_t o = off;
    off += (bytes + 255) & ~(size_t)255;
    return o;
  };
  int* deg_i = (int*)(ws + alloc((size_t)N * 4));
  int* row_start = (int*)(ws + alloc((size_t)(N + 1) * 4));
  int* cursor = (int*)(ws + alloc((size_t)N * 4));
  int* csr_src = (int*)(ws + alloc((size_t)E * 4));
  float* bufA = (float*)(ws + alloc((size_t)N * 128 * 4));
  float* bufB = (float*)(ws + alloc((size_t)N * 128 * 4));
  float* bufC = (float*)(ws + alloc((size_t)N * 128 * 4));
  float2* el1 = (float2*)(ws + alloc((size_t)N * 8));
  float2* er1 = (float2*)(ws + alloc((size_t)N * 8));
  float* el2 = (float*)(ws + alloc((size_t)N * 4));
  float* er2 = (float*)(ws + alloc((size_t)N * 4));
  float2* inv_s1 = (float2*)(ws + alloc((size_t)N * 8));
  float* inv_s2 = (float*)(ws + alloc((size_t)N * 4));
  (void)ws_size;
  (void)n_in;
  (void)out_size;

  float* z = bufA;                 // dead after sage_agg
  float* y = bufB;                 // interleaved; dead after sage_agg
  float* h0 = bufC;                // dead after feat1 gemm
  float* feat1 = bufA;             // interleaved; dead after gat1_agg
  float2* alpha1 = (float2*)bufB;  // dead after gat1_agg
  float* h1 = bufC;                // dead after feat2 gemm
  float* feat2 = bufA;             // ld 48
  float* alpha2 = bufB;

  hipMemsetAsync(deg_i, 0, (size_t)N * 4, stream);
  hipMemsetAsync(cursor, 0, (size_t)N * 4, stream);

  const int eb = (E + 255) / 256;
  const int nb4 = (N + 3) / 4;
  const int nb256 = (N + 255) / 256;

  deg_kernel<<<eb, 256, 0, stream>>>(dst, deg_i, E);
  scan_kernel<<<1, 1024, 0, stream>>>(deg_i, row_start, N);
  scatter_kernel<<<eb, 256, 0, stream>>>(src, dst, row_start, cursor, csr_src, E);

  // layer 0 fused: blockIdx.y=0 -> z = x@W_self (std), y=1 -> yI = x@W_neigh (ilv)
  {
    dim3 grid((N + 127) / 128, 2);
    gemm_f32<128, 128, 16, 8, 8><<<grid, 256, 0, stream>>>(
        x, 256, sage_w_self, sage_w_neigh, 128, z, y, 128, N, 128, 256, 0, 1);
  }
  sage_agg<<<nb4, 256, 0, stream>>>(z, (const float2*)y, row_start, csr_src, sage_b, h0, N);

  // GAT layer 1: feat1 = h0 @ gat1_w (interleaved)
  {
    dim3 grid((N + 63) / 64, 1);
    gemm_f32<64, 128, 16, 8, 8><<<grid, 128, 0, stream>>>(
        h0, 128, gat1_w, gat1_w, 128, feat1, feat1, 128, N, 128, 128, 1, 1);
  }
  elr1_kernel<<<nb4, 256, 0, stream>>>((const float2*)feat1, gat1_al, gat1_ar, el1, er1, N);
  attn1_kernel<<<nb256, 256, 0, stream>>>(el1, er1, row_start, csr_src, alpha1, inv_s1, N);
  gat1_agg<<<nb4, 256, 0, stream>>>((const float2*)feat1, alpha1, inv_s1, row_start,
                                    csr_src, gat1_b, h1, N);

  // GAT layer 2: feat2 = h1 @ gat2_w (ld 48, N=47)
  {
    dim3 grid((N + 63) / 64, 1);
    gemm_f32<64, 64, 16, 8, 4><<<grid, 128, 0, stream>>>(
        h1, 128, gat2_w, gat2_w, 47, feat2, feat2, 48, N, 47, 128, 0, 0);
  }
  elr2_kernel<<<nb4, 256, 0, stream>>>(feat2, gat2_al, gat2_ar, el2, er2, N);
  attn2_kernel<<<nb256, 256, 0, stream>>>(el2, er2, row_start, csr_src, alpha2, inv_s2, N);
  gat2_agg<<<nb4, 256, 0, stream>>>(feat2, alpha2, inv_s2, row_start, csr_src, gat2_b, out, N);
}